// Round 1
// baseline (794.761 us; speedup 1.0000x reference)
//
#include <hip/hip_runtime.h>
#include <hip/hip_bf16.h>
#include <stdint.h>

#define Bb 4
#define Nn 2048
#define Dd 1024
#define Aa 1024
#define Hh 16
#define HDd 64
#define DFF 4096
#define Mm (Bb*Nn)

typedef __bf16 bf16x8 __attribute__((ext_vector_type(8)));
typedef float f32x4 __attribute__((ext_vector_type(4)));
typedef unsigned short ushort_t;
using bf16 = __hip_bfloat16;

#define LOG2E 1.44269504088896340736f

__device__ inline ushort_t f2bfu(float f) {
  uint32_t u = __builtin_bit_cast(uint32_t, f);
  uint32_t r = u + 0x7fffu + ((u >> 16) & 1u);
  return (ushort_t)(r >> 16);
}

#define GLOAD_LDS16(gsrc, ldst)                                                \
  __builtin_amdgcn_global_load_lds(                                            \
      (const __attribute__((address_space(1))) void*)(gsrc),                   \
      (__attribute__((address_space(3))) void*)(ldst), 16, 0, 0)

// ---------------- f32 -> bf16 convert ----------------
__global__ __launch_bounds__(256) void cvt_k(const float* __restrict__ in,
                                             bf16* __restrict__ out, int n4) {
  int i = blockIdx.x * 256 + threadIdx.x;
  if (i >= n4) return;
  float4 v = reinterpret_cast<const float4*>(in)[i];
  ushort4 o;
  o.x = f2bfu(v.x); o.y = f2bfu(v.y); o.z = f2bfu(v.z); o.w = f2bfu(v.w);
  reinterpret_cast<ushort4*>(out)[i] = o;
}

// ---------------- LayerNorm (per row of 1024), f32 in -> bf16 out ----------------
__global__ __launch_bounds__(256) void ln_k(const float* __restrict__ x,
                                            const float* __restrict__ g,
                                            const float* __restrict__ b,
                                            bf16* __restrict__ out) {
  const int row = blockIdx.x;
  const int t = threadIdx.x;
  const float4 v = reinterpret_cast<const float4*>(x + (size_t)row * Dd)[t];
  float s = v.x + v.y + v.z + v.w;
  float sq = v.x * v.x + v.y * v.y + v.z * v.z + v.w * v.w;
#pragma unroll
  for (int m = 1; m < 64; m <<= 1) {
    s += __shfl_xor(s, m);
    sq += __shfl_xor(sq, m);
  }
  __shared__ float red[8];
  if ((t & 63) == 0) { red[t >> 6] = s; red[4 + (t >> 6)] = sq; }
  __syncthreads();
  s = red[0] + red[1] + red[2] + red[3];
  sq = red[4] + red[5] + red[6] + red[7];
  const float mean = s * (1.f / Dd);
  const float rstd = rsqrtf(sq * (1.f / Dd) - mean * mean + 1e-5f);
  const float4 gg = reinterpret_cast<const float4*>(g)[t];
  const float4 bb = reinterpret_cast<const float4*>(b)[t];
  ushort4 o;
  o.x = f2bfu((v.x - mean) * rstd * gg.x + bb.x);
  o.y = f2bfu((v.y - mean) * rstd * gg.y + bb.y);
  o.z = f2bfu((v.z - mean) * rstd * gg.z + bb.z);
  o.w = f2bfu((v.w - mean) * rstd * gg.w + bb.w);
  reinterpret_cast<ushort4*>(out + (size_t)row * Dd)[t] = o;
}

// ---------------- GEMM: C[M,N] = A[M,K] * W[N,K]^T + bias (+epilogue) ----------------
// EPI 0: +bias -> bf16 out; EPI 1: +bias+resid -> f32 out; EPI 2: relu(+bias) -> bf16
template <int EPI>
__global__ __launch_bounds__(256) void gemm_bt(const bf16* __restrict__ Amat,
                                               const bf16* __restrict__ Wmat,
                                               const float* __restrict__ bias,
                                               const float* __restrict__ resid,
                                               void* __restrict__ Cout,
                                               int Ndim, int Kdim) {
  __shared__ __align__(16) bf16 As[128 * 32];
  __shared__ __align__(16) bf16 Bs[128 * 32];
  const int tid = threadIdx.x;
  const int wave = tid >> 6, lane = tid & 63;
  const int g16 = lane >> 4, l15 = lane & 15;
  const int wm = wave >> 1, wn = wave & 1;
  const int tmb = blockIdx.y * 128, tnb = blockIdx.x * 128;

  const f32x4 zero = {0.f, 0.f, 0.f, 0.f};
  f32x4 acc[4][4];
#pragma unroll
  for (int f = 0; f < 4; f++)
#pragma unroll
    for (int g = 0; g < 4; g++) acc[f][g] = zero;

  for (int k0 = 0; k0 < Kdim; k0 += 32) {
    __syncthreads();
#pragma unroll
    for (int i = 0; i < 2; i++) {
      int c = i * 256 + tid;
      int row = c >> 2, cw = c & 3;
      GLOAD_LDS16(Amat + (size_t)(tmb + row) * Kdim + k0 + cw * 8,
                  As + (i * 256 + wave * 64) * 8);
      GLOAD_LDS16(Wmat + (size_t)(tnb + row) * Kdim + k0 + cw * 8,
                  Bs + (i * 256 + wave * 64) * 8);
    }
    __syncthreads();
    bf16x8 af[4], bfr[4];
#pragma unroll
    for (int f = 0; f < 4; f++) {
      af[f] = *reinterpret_cast<const bf16x8*>(As + (wm * 64 + f * 16 + l15) * 32 + g16 * 8);
      bfr[f] = *reinterpret_cast<const bf16x8*>(Bs + (wn * 64 + f * 16 + l15) * 32 + g16 * 8);
    }
#pragma unroll
    for (int f = 0; f < 4; f++)
#pragma unroll
      for (int g = 0; g < 4; g++)
        acc[f][g] = __builtin_amdgcn_mfma_f32_16x16x32_bf16(af[f], bfr[g], acc[f][g], 0, 0, 0);
  }

#pragma unroll
  for (int f = 0; f < 4; f++) {
#pragma unroll
    for (int g = 0; g < 4; g++) {
      const int col = tnb + wn * 64 + g * 16 + l15;
      const float bi = bias[col];
#pragma unroll
      for (int r = 0; r < 4; r++) {
        const int row = tmb + wm * 64 + f * 16 + g16 * 4 + r;
        float v = acc[f][g][r] + bi;
        if constexpr (EPI == 2) v = fmaxf(v, 0.f);
        if constexpr (EPI == 1) {
          ((float*)Cout)[(size_t)row * Ndim + col] = v + resid[(size_t)row * Ndim + col];
        } else {
          ((bf16*)Cout)[(size_t)row * Ndim + col] = __float2bfloat16(v);
        }
      }
    }
  }
}

// ---------------- V transpose: [B*N, A] per-head -> vt[bh][64 d][2048 n] ----------------
__global__ __launch_bounds__(256) void vtrans_k(const bf16* __restrict__ vm,
                                                bf16* __restrict__ vt) {
  const int bh = blockIdx.y, b = bh >> 4, h = bh & 15;
  const int n0 = blockIdx.x * 64;
  __shared__ __align__(16) bf16 tile[64 * 72];
  const int tid = threadIdx.x;
#pragma unroll
  for (int i = 0; i < 2; i++) {
    int c = i * 256 + tid;
    int r = c >> 3, cw = c & 7;
    bf16x8 v = *reinterpret_cast<const bf16x8*>(vm + (size_t)(b * Nn + n0 + r) * Aa + h * HDd + cw * 8);
    *reinterpret_cast<bf16x8*>(tile + r * 72 + cw * 8) = v;
  }
  __syncthreads();
#pragma unroll
  for (int i = 0; i < 2; i++) {
    int c = i * 256 + tid;
    int d = c >> 3, ncw = c & 7;
    alignas(16) bf16 tmp[8];
#pragma unroll
    for (int e = 0; e < 8; e++) tmp[e] = tile[(ncw * 8 + e) * 72 + d];
    *reinterpret_cast<bf16x8*>(vt + (size_t)(bh * HDd + d) * Nn + n0 + ncw * 8) =
        *reinterpret_cast<bf16x8*>(tmp);
  }
}

// ---------------- Flash attention: q,k [M,A] bf16, vt [bh][64][2048] -> o [M,A] bf16 ----------------
__global__ __launch_bounds__(256) void attn_k(const bf16* __restrict__ qm,
                                              const bf16* __restrict__ km,
                                              const bf16* __restrict__ vtm,
                                              bf16* __restrict__ om) {
  const int bh = blockIdx.y;
  const int b = bh >> 4, h = bh & 15;
  const int tid = threadIdx.x;
  const int wave = tid >> 6, lane = tid & 63;
  const int g16 = lane >> 4, l15 = lane & 15;
  __shared__ __align__(16) bf16 Ks[64 * 72];
  __shared__ __align__(16) bf16 Vs[64 * 72];
  __shared__ __align__(16) bf16 Ps[4][16 * 72];

  const int q0 = blockIdx.x * 64 + wave * 16;
  const size_t qrow = (size_t)(b * Nn + q0 + l15) * Aa + h * HDd;
  const bf16x8 aq0 = *reinterpret_cast<const bf16x8*>(qm + qrow + g16 * 8);
  const bf16x8 aq1 = *reinterpret_cast<const bf16x8*>(qm + qrow + 32 + g16 * 8);

  const f32x4 zero = {0.f, 0.f, 0.f, 0.f};
  f32x4 oacc[4] = {zero, zero, zero, zero};
  float mrun[4], lrun[4];
#pragma unroll
  for (int r = 0; r < 4; r++) { mrun[r] = -__builtin_inff(); lrun[r] = 0.f; }

  for (int j0 = 0; j0 < Nn; j0 += 64) {
    __syncthreads();
#pragma unroll
    for (int i = 0; i < 2; i++) {
      int c = i * 256 + tid;
      int r = c >> 3, cw = c & 7;
      bf16x8 kv = *reinterpret_cast<const bf16x8*>(km + (size_t)(b * Nn + j0 + r) * Aa + h * HDd + cw * 8);
      *reinterpret_cast<bf16x8*>(Ks + r * 72 + cw * 8) = kv;
      bf16x8 vv = *reinterpret_cast<const bf16x8*>(vtm + (size_t)(bh * HDd + r) * Nn + j0 + cw * 8);
      *reinterpret_cast<bf16x8*>(Vs + r * 72 + cw * 8) = vv;
    }
    __syncthreads();

    f32x4 sacc[4] = {zero, zero, zero, zero};
#pragma unroll
    for (int s = 0; s < 2; s++) {
      const bf16x8 a = s ? aq1 : aq0;
#pragma unroll
      for (int c = 0; c < 4; c++) {
        bf16x8 bk = *reinterpret_cast<const bf16x8*>(Ks + (c * 16 + l15) * 72 + s * 32 + g16 * 8);
        sacc[c] = __builtin_amdgcn_mfma_f32_16x16x32_bf16(a, bk, sacc[c], 0, 0, 0);
      }
    }
#pragma unroll
    for (int c = 0; c < 4; c++) sacc[c] *= 0.03125f;  // D^-0.5

    float tmax[4];
#pragma unroll
    for (int r = 0; r < 4; r++) {
      float m0 = fmaxf(fmaxf(sacc[0][r], sacc[1][r]), fmaxf(sacc[2][r], sacc[3][r]));
#pragma unroll
      for (int msk = 1; msk < 16; msk <<= 1) m0 = fmaxf(m0, __shfl_xor(m0, msk));
      tmax[r] = m0;
    }
    float corr[4], psum[4];
#pragma unroll
    for (int r = 0; r < 4; r++) {
      float nm = fmaxf(mrun[r], tmax[r]);
      corr[r] = exp2f((mrun[r] - nm) * LOG2E);
      mrun[r] = nm;
      psum[r] = 0.f;
    }
#pragma unroll
    for (int c = 0; c < 4; c++) {
#pragma unroll
      for (int r = 0; r < 4; r++) {
        float p = exp2f((sacc[c][r] - mrun[r]) * LOG2E);
        psum[r] += p;
        Ps[wave][(g16 * 4 + r) * 72 + c * 16 + l15] = __float2bfloat16(p);
      }
    }
#pragma unroll
    for (int r = 0; r < 4; r++) {
#pragma unroll
      for (int msk = 1; msk < 16; msk <<= 1) psum[r] += __shfl_xor(psum[r], msk);
      lrun[r] = lrun[r] * corr[r] + psum[r];
    }
#pragma unroll
    for (int c = 0; c < 4; c++) {
      f32x4 t = oacc[c];
      t[0] *= corr[0]; t[1] *= corr[1]; t[2] *= corr[2]; t[3] *= corr[3];
      oacc[c] = t;
    }
    asm volatile("s_waitcnt lgkmcnt(0)" ::: "memory");
    bf16x8 ap[2];
    ap[0] = *reinterpret_cast<const bf16x8*>(&Ps[wave][l15 * 72 + g16 * 8]);
    ap[1] = *reinterpret_cast<const bf16x8*>(&Ps[wave][l15 * 72 + 32 + g16 * 8]);
#pragma unroll
    for (int c = 0; c < 4; c++) {
#pragma unroll
      for (int s = 0; s < 2; s++) {
        bf16x8 bv = *reinterpret_cast<const bf16x8*>(Vs + (c * 16 + l15) * 72 + s * 32 + g16 * 8);
        oacc[c] = __builtin_amdgcn_mfma_f32_16x16x32_bf16(ap[s], bv, oacc[c], 0, 0, 0);
      }
    }
  }

#pragma unroll
  for (int c = 0; c < 4; c++) {
#pragma unroll
    for (int r = 0; r < 4; r++) {
      const float inv = 1.f / lrun[r];
      om[(size_t)(b * Nn + q0 + g16 * 4 + r) * Aa + h * HDd + c * 16 + l15] =
          __float2bfloat16(oacc[c][r] * inv);
    }
  }
}

// ---------------- host launch ----------------
extern "C" void kernel_launch(void* const* d_in, const int* in_sizes, int n_in,
                              void* d_out, int out_size, void* d_ws, size_t ws_size,
                              hipStream_t stream) {
  const float* x    = (const float*)d_in[0];
  const float* wq   = (const float*)d_in[2];
  const float* bq   = (const float*)d_in[3];
  const float* wk   = (const float*)d_in[4];
  const float* bk   = (const float*)d_in[5];
  const float* wv   = (const float*)d_in[6];
  const float* bv   = (const float*)d_in[7];
  const float* wo   = (const float*)d_in[8];
  const float* bo   = (const float*)d_in[9];
  const float* w1   = (const float*)d_in[10];
  const float* b1   = (const float*)d_in[11];
  const float* w2   = (const float*)d_in[12];
  const float* b2   = (const float*)d_in[13];
  const float* ln1g = (const float*)d_in[14];
  const float* ln1b = (const float*)d_in[15];
  const float* ln2g = (const float*)d_in[16];
  const float* ln2b = (const float*)d_in[17];
  float* out = (float*)d_out;

  uint8_t* ws = (uint8_t*)d_ws;
  const size_t MB = (size_t)1 << 20;
  bf16* wq_b = (bf16*)(ws + 0 * MB);
  bf16* wk_b = (bf16*)(ws + 2 * MB);
  bf16* wv_b = (bf16*)(ws + 4 * MB);
  bf16* wo_b = (bf16*)(ws + 6 * MB);
  bf16* w1_b = (bf16*)(ws + 8 * MB);
  bf16* w2_b = (bf16*)(ws + 16 * MB);
  bf16* h_b  = (bf16*)(ws + 24 * MB);  // reused as h2 after attention block
  bf16* q_b  = (bf16*)(ws + 40 * MB);
  bf16* k_b  = (bf16*)(ws + 56 * MB);
  bf16* v_b  = (bf16*)(ws + 72 * MB);
  bf16* vt_b = (bf16*)(ws + 88 * MB);
  bf16* o_b  = (bf16*)(ws + 104 * MB);
  float* x2  = (float*)(ws + 120 * MB);
  bf16* mid  = (bf16*)(ws + 40 * MB);  // overlaps q/k/v/vt (dead by then)

  cvt_k<<<1024, 256, 0, stream>>>(wq, wq_b, 262144);
  cvt_k<<<1024, 256, 0, stream>>>(wk, wk_b, 262144);
  cvt_k<<<1024, 256, 0, stream>>>(wv, wv_b, 262144);
  cvt_k<<<1024, 256, 0, stream>>>(wo, wo_b, 262144);
  cvt_k<<<4096, 256, 0, stream>>>(w1, w1_b, 1048576);
  cvt_k<<<4096, 256, 0, stream>>>(w2, w2_b, 1048576);

  ln_k<<<Mm, 256, 0, stream>>>(x, ln1g, ln1b, h_b);

  dim3 gP(Aa / 128, Mm / 128);  // (8, 64)
  gemm_bt<0><<<gP, 256, 0, stream>>>(h_b, wq_b, bq, nullptr, q_b, Aa, Dd);
  gemm_bt<0><<<gP, 256, 0, stream>>>(h_b, wk_b, bk, nullptr, k_b, Aa, Dd);
  gemm_bt<0><<<gP, 256, 0, stream>>>(h_b, wv_b, bv, nullptr, v_b, Aa, Dd);

  vtrans_k<<<dim3(Nn / 64, Bb * Hh), 256, 0, stream>>>(v_b, vt_b);
  attn_k<<<dim3(Nn / 64, Bb * Hh), 256, 0, stream>>>(q_b, k_b, vt_b, o_b);

  gemm_bt<1><<<gP, 256, 0, stream>>>(o_b, wo_b, bo, x, x2, Dd, Aa);

  ln_k<<<Mm, 256, 0, stream>>>(x2, ln2g, ln2b, h_b);

  dim3 gF(DFF / 128, Mm / 128);  // (32, 64)
  gemm_bt<2><<<gF, 256, 0, stream>>>(h_b, w1_b, b1, nullptr, mid, DFF, Dd);
  gemm_bt<1><<<gP, 256, 0, stream>>>(mid, w2_b, b2, x2, out, Dd, DFF);
}

// Round 2
// 692.508 us; speedup vs baseline: 1.1477x; 1.1477x over previous
//
#include <hip/hip_runtime.h>
#include <hip/hip_bf16.h>
#include <stdint.h>

#define Bb 4
#define Nn 2048
#define Dd 1024
#define Aa 1024
#define Hh 16
#define HDd 64
#define DFF 4096
#define Mm (Bb*Nn)

typedef __bf16 bf16x8 __attribute__((ext_vector_type(8)));
typedef float f32x4 __attribute__((ext_vector_type(4)));
typedef float f32x16 __attribute__((ext_vector_type(16)));
typedef uint32_t u32x4v __attribute__((ext_vector_type(4)));
typedef unsigned short ushort_t;
using bf16 = __hip_bfloat16;

#define LOG2E 1.44269504088896340736f

__device__ inline ushort_t f2bfu(float f) {
  uint32_t u = __builtin_bit_cast(uint32_t, f);
  uint32_t r = u + 0x7fffu + ((u >> 16) & 1u);
  return (ushort_t)(r >> 16);
}
__device__ inline uint32_t pk2(float lo, float hi) {
  return ((uint32_t)f2bfu(hi) << 16) | (uint32_t)f2bfu(lo);
}

#define GLOAD_LDS16(gsrc, ldst)                                                \
  __builtin_amdgcn_global_load_lds(                                            \
      (const __attribute__((address_space(1))) void*)(gsrc),                   \
      (__attribute__((address_space(3))) void*)(ldst), 16, 0, 0)

// ---------------- f32 -> bf16 convert ----------------
__global__ __launch_bounds__(256) void cvt_k(const float* __restrict__ in,
                                             bf16* __restrict__ out, int n4) {
  int i = blockIdx.x * 256 + threadIdx.x;
  if (i >= n4) return;
  float4 v = reinterpret_cast<const float4*>(in)[i];
  ushort4 o;
  o.x = f2bfu(v.x); o.y = f2bfu(v.y); o.z = f2bfu(v.z); o.w = f2bfu(v.w);
  reinterpret_cast<ushort4*>(out)[i] = o;
}

// ---------------- LayerNorm (per row of 1024), f32 in -> bf16 out ----------------
__global__ __launch_bounds__(256) void ln_k(const float* __restrict__ x,
                                            const float* __restrict__ g,
                                            const float* __restrict__ b,
                                            bf16* __restrict__ out) {
  const int row = blockIdx.x;
  const int t = threadIdx.x;
  const float4 v = reinterpret_cast<const float4*>(x + (size_t)row * Dd)[t];
  float s = v.x + v.y + v.z + v.w;
  float sq = v.x * v.x + v.y * v.y + v.z * v.z + v.w * v.w;
#pragma unroll
  for (int m = 1; m < 64; m <<= 1) {
    s += __shfl_xor(s, m);
    sq += __shfl_xor(sq, m);
  }
  __shared__ float red[8];
  if ((t & 63) == 0) { red[t >> 6] = s; red[4 + (t >> 6)] = sq; }
  __syncthreads();
  s = red[0] + red[1] + red[2] + red[3];
  sq = red[4] + red[5] + red[6] + red[7];
  const float mean = s * (1.f / Dd);
  const float rstd = rsqrtf(sq * (1.f / Dd) - mean * mean + 1e-5f);
  const float4 gg = reinterpret_cast<const float4*>(g)[t];
  const float4 bb = reinterpret_cast<const float4*>(b)[t];
  ushort4 o;
  o.x = f2bfu((v.x - mean) * rstd * gg.x + bb.x);
  o.y = f2bfu((v.y - mean) * rstd * gg.y + bb.y);
  o.z = f2bfu((v.z - mean) * rstd * gg.z + bb.z);
  o.w = f2bfu((v.w - mean) * rstd * gg.w + bb.w);
  reinterpret_cast<ushort4*>(out + (size_t)row * Dd)[t] = o;
}

// ---------------- GEMM: C[M,N] = (A[M,K] * W[N,K]^T + bias) * ascale (+epilogue) ----------------
// EPI 0: -> bf16 out; EPI 1: +resid -> f32 out; EPI 2: relu -> bf16
template <int EPI>
__global__ __launch_bounds__(256) void gemm_bt(const bf16* __restrict__ Amat,
                                               const bf16* __restrict__ Wmat,
                                               const float* __restrict__ bias,
                                               const float* __restrict__ resid,
                                               void* __restrict__ Cout,
                                               int Ndim, int Kdim, float ascale) {
  __shared__ __align__(16) bf16 As[128 * 32];
  __shared__ __align__(16) bf16 Bs[128 * 32];
  const int tid = threadIdx.x;
  const int wave = tid >> 6, lane = tid & 63;
  const int g16 = lane >> 4, l15 = lane & 15;
  const int wm = wave >> 1, wn = wave & 1;
  const int tmb = blockIdx.y * 128, tnb = blockIdx.x * 128;

  const f32x4 zero = {0.f, 0.f, 0.f, 0.f};
  f32x4 acc[4][4];
#pragma unroll
  for (int f = 0; f < 4; f++)
#pragma unroll
    for (int g = 0; g < 4; g++) acc[f][g] = zero;

  for (int k0 = 0; k0 < Kdim; k0 += 32) {
    __syncthreads();
#pragma unroll
    for (int i = 0; i < 2; i++) {
      int c = i * 256 + tid;
      int row = c >> 2, cw = c & 3;
      GLOAD_LDS16(Amat + (size_t)(tmb + row) * Kdim + k0 + cw * 8,
                  As + (i * 256 + wave * 64) * 8);
      GLOAD_LDS16(Wmat + (size_t)(tnb + row) * Kdim + k0 + cw * 8,
                  Bs + (i * 256 + wave * 64) * 8);
    }
    __syncthreads();
    bf16x8 af[4], bfr[4];
#pragma unroll
    for (int f = 0; f < 4; f++) {
      af[f] = *reinterpret_cast<const bf16x8*>(As + (wm * 64 + f * 16 + l15) * 32 + g16 * 8);
      bfr[f] = *reinterpret_cast<const bf16x8*>(Bs + (wn * 64 + f * 16 + l15) * 32 + g16 * 8);
    }
#pragma unroll
    for (int f = 0; f < 4; f++)
#pragma unroll
      for (int g = 0; g < 4; g++)
        acc[f][g] = __builtin_amdgcn_mfma_f32_16x16x32_bf16(af[f], bfr[g], acc[f][g], 0, 0, 0);
  }

#pragma unroll
  for (int f = 0; f < 4; f++) {
#pragma unroll
    for (int g = 0; g < 4; g++) {
      const int col = tnb + wn * 64 + g * 16 + l15;
      const float bi = bias[col];
#pragma unroll
      for (int r = 0; r < 4; r++) {
        const int row = tmb + wm * 64 + f * 16 + g16 * 4 + r;
        float v = (acc[f][g][r] + bi) * ascale;
        if constexpr (EPI == 2) v = fmaxf(v, 0.f);
        if constexpr (EPI == 1) {
          ((float*)Cout)[(size_t)row * Ndim + col] = v + resid[(size_t)row * Ndim + col];
        } else {
          ((bf16*)Cout)[(size_t)row * Ndim + col] = __float2bfloat16(v);
        }
      }
    }
  }
}

// ---------------- V transpose: [B*N, A] per-head -> vt[bh][64 d][2048 n] ----------------
__global__ __launch_bounds__(256) void vtrans_k(const bf16* __restrict__ vm,
                                                bf16* __restrict__ vt) {
  const int bh = blockIdx.y, b = bh >> 4, h = bh & 15;
  const int n0 = blockIdx.x * 64;
  __shared__ __align__(16) bf16 tile[64 * 72];
  const int tid = threadIdx.x;
#pragma unroll
  for (int i = 0; i < 2; i++) {
    int c = i * 256 + tid;
    int r = c >> 3, cw = c & 7;
    bf16x8 v = *reinterpret_cast<const bf16x8*>(vm + (size_t)(b * Nn + n0 + r) * Aa + h * HDd + cw * 8);
    *reinterpret_cast<bf16x8*>(tile + r * 72 + cw * 8) = v;
  }
  __syncthreads();
#pragma unroll
  for (int i = 0; i < 2; i++) {
    int c = i * 256 + tid;
    int d = c >> 3, ncw = c & 7;
    alignas(16) bf16 tmp[8];
#pragma unroll
    for (int e = 0; e < 8; e++) tmp[e] = tile[(ncw * 8 + e) * 72 + d];
    *reinterpret_cast<bf16x8*>(vt + (size_t)(bh * HDd + d) * Nn + n0 + ncw * 8) =
        *reinterpret_cast<bf16x8*>(tmp);
  }
}

// ---------------- Flash attention, swapped-operand 32x32 MFMA ----------------
// 4 waves x 32 q-rows = 128 q-rows/block. KV tile 64. K,Vt staged in
// XOR-swizzled LDS via global_load_lds (pre-swizzled source, rule #21).
// S^T = mfma(K, Q): lane holds 32 P values for q = lane&31 (keys with
// bit2 == lane>>5). O^T = mfma(Vt, P^T): col = q -> per-lane scalar m/l.
__global__ __launch_bounds__(256) void attn_k(const bf16* __restrict__ qm,
                                              const bf16* __restrict__ km,
                                              const bf16* __restrict__ vtm,
                                              bf16* __restrict__ om) {
  const int bh = blockIdx.y, b = bh >> 4, h = bh & 15;
  const int tid = threadIdx.x;
  const int wv = tid >> 6, lane = tid & 63;
  const int l31 = lane & 31, hi = lane >> 5, l7 = lane & 7;

  // SMEM elems: K[buf] = +buf*4096, Vt[buf] = +8192+buf*4096 (each 64x64 bf16)
  __shared__ __align__(16) bf16 SMEM[16384];

  const int q0 = blockIdx.x * 128 + wv * 32;

  // Q fragments (B-operand): lane holds Q[q0+l31][16*dk + 8*hi + 0..7]
  bf16x8 qf[4];
  const size_t qbase = (size_t)(b * Nn + q0 + l31) * Aa + h * HDd + hi * 8;
#pragma unroll
  for (int dk = 0; dk < 4; dk++)
    qf[dk] = *reinterpret_cast<const bf16x8*>(qm + qbase + dk * 16);

  f32x16 oacc[2];
#pragma unroll
  for (int d = 0; d < 2; d++)
#pragma unroll
    for (int r = 0; r < 16; r++) oacc[d][r] = 0.f;
  float mrun = -__builtin_huge_valf(), lrun = 0.f;

  // ---- staging: 2 x 16B per thread per matrix, source pre-swizzled ----
#define STAGE(buf, j0)                                                         \
  {                                                                            \
    _Pragma("unroll")                                                          \
    for (int i = 0; i < 2; i++) {                                              \
      int id = i * 256 + tid;                                                  \
      int row = id >> 3, c = id & 7;                                           \
      int cs = c ^ (row & 7);                                                  \
      GLOAD_LDS16(km + (size_t)(b * Nn + (j0) + row) * Aa + h * HDd + cs * 8,  \
                  SMEM + (buf) * 4096 + (i * 256 + wv * 64) * 8);              \
      GLOAD_LDS16(vtm + (size_t)(bh * 64 + row) * Nn + (j0) + cs * 8,          \
                  SMEM + 8192 + (buf) * 4096 + (i * 256 + wv * 64) * 8);       \
    }                                                                          \
  }

  STAGE(0, 0)
  asm volatile("s_waitcnt vmcnt(0)" ::: "memory");
  __builtin_amdgcn_s_barrier();

  const int NT = Nn / 64;
  for (int jt = 0; jt < NT; jt++) {
    const int cur = jt & 1;
    if (jt + 1 < NT) STAGE(cur ^ 1, (jt + 1) * 64)
    const bf16* KBc = SMEM + cur * 4096;
    const bf16* VBc = SMEM + 8192 + cur * 4096;

    // ---- QK^T (swapped): sacc[t] = S^T tile rows 32t..32t+31, col q=l31 ----
    f32x16 sacc[2];
#pragma unroll
    for (int t = 0; t < 2; t++)
#pragma unroll
      for (int r = 0; r < 16; r++) sacc[t][r] = 0.f;
#pragma unroll
    for (int t = 0; t < 2; t++) {
#pragma unroll
      for (int dk = 0; dk < 4; dk++) {
        const int row = t * 32 + l31;
        const bf16x8 kf = *reinterpret_cast<const bf16x8*>(
            KBc + row * 64 + (((hi + 2 * dk) ^ l7) * 8));
        sacc[t] = __builtin_amdgcn_mfma_f32_32x32x16_bf16(kf, qf[dk], sacc[t], 0, 0, 0);
      }
    }

    // ---- online softmax (per-lane: one q, 32 of 64 keys) ----
    float tm = sacc[0][0];
#pragma unroll
    for (int r = 1; r < 16; r++) tm = fmaxf(tm, sacc[0][r]);
#pragma unroll
    for (int r = 0; r < 16; r++) tm = fmaxf(tm, sacc[1][r]);
    tm = fmaxf(tm, __shfl_xor(tm, 32));
    const float nm = fmaxf(mrun, tm);
    const float corr = exp2f((mrun - nm) * LOG2E);
    mrun = nm;

    float ps = 0.f;
    uint32_t w[8][2];
#pragma unroll
    for (int a = 0; a < 8; a++) {
#pragma unroll
      for (int bb = 0; bb < 2; bb++) {
        const int t = a >> 2, r = (a & 3) * 4 + 2 * bb;
        const float p0 = exp2f((sacc[t][r] - nm) * LOG2E);
        const float p1 = exp2f((sacc[t][r + 1] - nm) * LOG2E);
        ps += p0 + p1;
        w[a][bb] = pk2(p0, p1);
      }
    }
    ps += __shfl_xor(ps, 32);
    lrun = lrun * corr + ps;
#pragma unroll
    for (int d = 0; d < 2; d++)
#pragma unroll
      for (int r = 0; r < 16; r++) oacc[d][r] *= corr;

    // ---- PV (swapped): oacc[dh] += mfma(Vt-frag, P^T-frag) ----
#pragma unroll
    for (int ks = 0; ks < 4; ks++) {
      const uint32_t wl0 = hi ? w[2 * ks + 1][0] : w[2 * ks][0];
      const uint32_t wl1 = hi ? w[2 * ks + 1][1] : w[2 * ks][1];
      const uint32_t ws0 = hi ? w[2 * ks][0] : w[2 * ks + 1][0];
      const uint32_t ws1 = hi ? w[2 * ks][1] : w[2 * ks + 1][1];
      const uint32_t wr0 = __shfl_xor(ws0, 32);
      const uint32_t wr1 = __shfl_xor(ws1, 32);
      u32x4v w4;
      w4[0] = hi ? wr0 : wl0;
      w4[1] = hi ? wr1 : wl1;
      w4[2] = hi ? wl0 : wr0;
      w4[3] = hi ? wl1 : wr1;
      const bf16x8 pf = __builtin_bit_cast(bf16x8, w4);
#pragma unroll
      for (int dh = 0; dh < 2; dh++) {
        const int row = dh * 32 + l31;
        const bf16x8 vf = *reinterpret_cast<const bf16x8*>(
            VBc + row * 64 + (((hi + 2 * ks) ^ l7) * 8));
        oacc[dh] = __builtin_amdgcn_mfma_f32_32x32x16_bf16(vf, pf, oacc[dh], 0, 0, 0);
      }
    }

    if (jt + 1 < NT) {
      asm volatile("s_waitcnt vmcnt(0)" ::: "memory");
      __builtin_amdgcn_s_barrier();
    }
  }

  // ---- epilogue: O^T regs -> LDS transpose -> coalesced global store ----
  __syncthreads();  // all K/V consumption done before LDS reuse
  bf16* ob = SMEM + wv * (32 * 72);
  const float inv = 1.f / lrun;
#pragma unroll
  for (int dh = 0; dh < 2; dh++) {
#pragma unroll
    for (int r = 0; r < 16; r++) {
      const int d = (r & 3) + 8 * (r >> 2) + 4 * hi + 32 * dh;
      ob[l31 * 72 + d] = __float2bfloat16(oacc[dh][r] * inv);
    }
  }
  __syncthreads();
  const int qp = lane >> 1, half = lane & 1;
  const size_t orow = (size_t)(b * Nn + q0 + qp) * Aa + h * HDd + half * 32;
#pragma unroll
  for (int e = 0; e < 2; e++) {
    bf16x8 v0 = *reinterpret_cast<const bf16x8*>(ob + qp * 72 + half * 32 + e * 16);
    bf16x8 v1 = *reinterpret_cast<const bf16x8*>(ob + qp * 72 + half * 32 + e * 16 + 8);
    *reinterpret_cast<bf16x8*>(om + orow + e * 16) = v0;
    *reinterpret_cast<bf16x8*>(om + orow + e * 16 + 8) = v1;
  }
}

// ---------------- host launch ----------------
extern "C" void kernel_launch(void* const* d_in, const int* in_sizes, int n_in,
                              void* d_out, int out_size, void* d_ws, size_t ws_size,
                              hipStream_t stream) {
  const float* x    = (const float*)d_in[0];
  const float* wq   = (const float*)d_in[2];
  const float* bq   = (const float*)d_in[3];
  const float* wk   = (const float*)d_in[4];
  const float* bk   = (const float*)d_in[5];
  const float* wv   = (const float*)d_in[6];
  const float* bv   = (const float*)d_in[7];
  const float* wo   = (const float*)d_in[8];
  const float* bo   = (const float*)d_in[9];
  const float* w1   = (const float*)d_in[10];
  const float* b1   = (const float*)d_in[11];
  const float* w2   = (const float*)d_in[12];
  const float* b2   = (const float*)d_in[13];
  const float* ln1g = (const float*)d_in[14];
  const float* ln1b = (const float*)d_in[15];
  const float* ln2g = (const float*)d_in[16];
  const float* ln2b = (const float*)d_in[17];
  float* out = (float*)d_out;

  uint8_t* ws = (uint8_t*)d_ws;
  const size_t MB = (size_t)1 << 20;
  bf16* wq_b = (bf16*)(ws + 0 * MB);
  bf16* wk_b = (bf16*)(ws + 2 * MB);
  bf16* wv_b = (bf16*)(ws + 4 * MB);
  bf16* wo_b = (bf16*)(ws + 6 * MB);
  bf16* w1_b = (bf16*)(ws + 8 * MB);
  bf16* w2_b = (bf16*)(ws + 16 * MB);
  bf16* h_b  = (bf16*)(ws + 24 * MB);  // reused as h2 after attention block
  bf16* q_b  = (bf16*)(ws + 40 * MB);
  bf16* k_b  = (bf16*)(ws + 56 * MB);
  bf16* v_b  = (bf16*)(ws + 72 * MB);
  bf16* vt_b = (bf16*)(ws + 88 * MB);
  bf16* o_b  = (bf16*)(ws + 104 * MB);
  float* x2  = (float*)(ws + 120 * MB);
  bf16* mid  = (bf16*)(ws + 40 * MB);  // overlaps q/k/v/vt (dead by then)

  const float SCALE = 0.03125f;  // 1024^-0.5

  cvt_k<<<1024, 256, 0, stream>>>(wq, wq_b, 262144);
  cvt_k<<<1024, 256, 0, stream>>>(wk, wk_b, 262144);
  cvt_k<<<1024, 256, 0, stream>>>(wv, wv_b, 262144);
  cvt_k<<<1024, 256, 0, stream>>>(wo, wo_b, 262144);
  cvt_k<<<4096, 256, 0, stream>>>(w1, w1_b, 1048576);
  cvt_k<<<4096, 256, 0, stream>>>(w2, w2_b, 1048576);

  ln_k<<<Mm, 256, 0, stream>>>(x, ln1g, ln1b, h_b);

  dim3 gP(Aa / 128, Mm / 128);  // (8, 64)
  gemm_bt<0><<<gP, 256, 0, stream>>>(h_b, wq_b, bq, nullptr, q_b, Aa, Dd, SCALE);
  gemm_bt<0><<<gP, 256, 0, stream>>>(h_b, wk_b, bk, nullptr, k_b, Aa, Dd, 1.f);
  gemm_bt<0><<<gP, 256, 0, stream>>>(h_b, wv_b, bv, nullptr, v_b, Aa, Dd, 1.f);

  vtrans_k<<<dim3(Nn / 64, Bb * Hh), 256, 0, stream>>>(v_b, vt_b);
  attn_k<<<dim3(Nn / 128, Bb * Hh), 256, 0, stream>>>(q_b, k_b, vt_b, o_b);

  gemm_bt<1><<<gP, 256, 0, stream>>>(o_b, wo_b, bo, x, x2, Dd, Aa, 1.f);

  ln_k<<<Mm, 256, 0, stream>>>(x2, ln2g, ln2b, h_b);

  dim3 gF(DFF / 128, Mm / 128);  // (32, 64)
  gemm_bt<2><<<gF, 256, 0, stream>>>(h_b, w1_b, b1, nullptr, mid, DFF, Dd, 1.f);
  gemm_bt<1><<<gP, 256, 0, stream>>>(mid, w2_b, b2, x2, out, Dd, DFF, 1.f);
}

// Round 4
// 659.221 us; speedup vs baseline: 1.2056x; 1.0505x over previous
//
#include <hip/hip_runtime.h>
#include <hip/hip_bf16.h>
#include <stdint.h>

#define Bb 4
#define Nn 2048
#define Dd 1024
#define Aa 1024
#define Hh 16
#define HDd 64
#define DFF 4096
#define Mm (Bb*Nn)

typedef __bf16 bf16x8 __attribute__((ext_vector_type(8)));
typedef float f32x4 __attribute__((ext_vector_type(4)));
typedef float f32x16 __attribute__((ext_vector_type(16)));
typedef uint32_t u32x4v __attribute__((ext_vector_type(4)));
typedef unsigned short ushort_t;
using bf16 = __hip_bfloat16;

#define LOG2E 1.44269504088896340736f

__device__ inline ushort_t f2bfu(float f) {
  uint32_t u = __builtin_bit_cast(uint32_t, f);
  uint32_t r = u + 0x7fffu + ((u >> 16) & 1u);
  return (ushort_t)(r >> 16);
}

#define GLOAD_LDS16(gsrc, ldst)                                                \
  __builtin_amdgcn_global_load_lds(                                            \
      (const __attribute__((address_space(1))) void*)(gsrc),                   \
      (__attribute__((address_space(3))) void*)(ldst), 16, 0, 0)

// ---------------- f32 -> bf16 convert ----------------
__global__ __launch_bounds__(256) void cvt_k(const float* __restrict__ in,
                                             bf16* __restrict__ out, int n4) {
  int i = blockIdx.x * 256 + threadIdx.x;
  if (i >= n4) return;
  float4 v = reinterpret_cast<const float4*>(in)[i];
  ushort4 o;
  o.x = f2bfu(v.x); o.y = f2bfu(v.y); o.z = f2bfu(v.z); o.w = f2bfu(v.w);
  reinterpret_cast<ushort4*>(out)[i] = o;
}

// ---------------- LayerNorm (per row of 1024), f32 in -> bf16 out ----------------
__global__ __launch_bounds__(256) void ln_k(const float* __restrict__ x,
                                            const float* __restrict__ g,
                                            const float* __restrict__ b,
                                            bf16* __restrict__ out) {
  const int row = blockIdx.x;
  const int t = threadIdx.x;
  const float4 v = reinterpret_cast<const float4*>(x + (size_t)row * Dd)[t];
  float s = v.x + v.y + v.z + v.w;
  float sq = v.x * v.x + v.y * v.y + v.z * v.z + v.w * v.w;
#pragma unroll
  for (int m = 1; m < 64; m <<= 1) {
    s += __shfl_xor(s, m);
    sq += __shfl_xor(sq, m);
  }
  __shared__ float red[8];
  if ((t & 63) == 0) { red[t >> 6] = s; red[4 + (t >> 6)] = sq; }
  __syncthreads();
  s = red[0] + red[1] + red[2] + red[3];
  sq = red[4] + red[5] + red[6] + red[7];
  const float mean = s * (1.f / Dd);
  const float rstd = rsqrtf(sq * (1.f / Dd) - mean * mean + 1e-5f);
  const float4 gg = reinterpret_cast<const float4*>(g)[t];
  const float4 bb = reinterpret_cast<const float4*>(b)[t];
  ushort4 o;
  o.x = f2bfu((v.x - mean) * rstd * gg.x + bb.x);
  o.y = f2bfu((v.y - mean) * rstd * gg.y + bb.y);
  o.z = f2bfu((v.z - mean) * rstd * gg.z + bb.z);
  o.w = f2bfu((v.w - mean) * rstd * gg.w + bb.w);
  reinterpret_cast<ushort4*>(out + (size_t)row * Dd)[t] = o;
}

// ---------------- GEMM: C[M,N] = (A[M,K] * W[N,K]^T + bias) * ascale (+epilogue) ----------------
// LDS tile: 128 rows x 32 cols bf16, packed 2 matrix rows per 128B lds_row,
// slot8 = (r&1)*4 + colslot, stored at slot8 ^ (lds_row&7)  [T2 swizzle,
// applied on BOTH staging-source and read per rule #21 -> 2-way conflict = free]
// EPI 0: -> bf16 out; EPI 1: +resid -> f32 out; EPI 2: relu -> bf16
template <int EPI>
__global__ __launch_bounds__(256) void gemm_bt(const bf16* __restrict__ Amat,
                                               const bf16* __restrict__ Wmat,
                                               const float* __restrict__ bias,
                                               const float* __restrict__ resid,
                                               void* __restrict__ Cout,
                                               int Ndim, int Kdim, float ascale) {
  __shared__ __align__(16) bf16 As[128 * 32];
  __shared__ __align__(16) bf16 Bs[128 * 32];
  const int tid = threadIdx.x;
  const int wave = tid >> 6, lane = tid & 63;
  const int g16 = lane >> 4, l15 = lane & 15;
  const int wm = wave >> 1, wn = wave & 1;
  const int tmb = blockIdx.y * 128, tnb = blockIdx.x * 128;

  const f32x4 zero = {0.f, 0.f, 0.f, 0.f};
  f32x4 acc[4][4];
#pragma unroll
  for (int f = 0; f < 4; f++)
#pragma unroll
    for (int g = 0; g < 4; g++) acc[f][g] = zero;

  for (int k0 = 0; k0 < Kdim; k0 += 32) {
    __syncthreads();
#pragma unroll
    for (int i = 0; i < 2; i++) {
      int t = i * 256 + tid;           // 0..511 : 16B chunk id
      int lr = t >> 3;                 // lds_row (128B each)
      int s8 = (t & 7) ^ (lr & 7);     // inverse swizzle
      int row = lr * 2 + (s8 >> 2);    // matrix row
      int cs = s8 & 3;                 // 8-elem col slot
      GLOAD_LDS16(Amat + (size_t)(tmb + row) * Kdim + k0 + cs * 8,
                  As + (i * 256 + wave * 64) * 8);
      GLOAD_LDS16(Wmat + (size_t)(tnb + row) * Kdim + k0 + cs * 8,
                  Bs + (i * 256 + wave * 64) * 8);
    }
    __syncthreads();
    bf16x8 af[4], bfr[4];
#pragma unroll
    for (int f = 0; f < 4; f++) {
      const int rA = wm * 64 + f * 16 + l15;
      const int rB = wn * 64 + f * 16 + l15;
      af[f] = *reinterpret_cast<const bf16x8*>(
          As + (rA >> 1) * 64 + (((((rA & 1) << 2) + g16) ^ ((rA >> 1) & 7)) * 8));
      bfr[f] = *reinterpret_cast<const bf16x8*>(
          Bs + (rB >> 1) * 64 + (((((rB & 1) << 2) + g16) ^ ((rB >> 1) & 7)) * 8));
    }
#pragma unroll
    for (int f = 0; f < 4; f++)
#pragma unroll
      for (int g = 0; g < 4; g++)
        acc[f][g] = __builtin_amdgcn_mfma_f32_16x16x32_bf16(af[f], bfr[g], acc[f][g], 0, 0, 0);
  }

#pragma unroll
  for (int f = 0; f < 4; f++) {
#pragma unroll
    for (int g = 0; g < 4; g++) {
      const int col = tnb + wn * 64 + g * 16 + l15;
      const float bi = bias[col];
#pragma unroll
      for (int r = 0; r < 4; r++) {
        const int row = tmb + wm * 64 + f * 16 + g16 * 4 + r;
        float v = (acc[f][g][r] + bi) * ascale;
        if constexpr (EPI == 2) v = fmaxf(v, 0.f);
        if constexpr (EPI == 1) {
          ((float*)Cout)[(size_t)row * Ndim + col] = v + resid[(size_t)row * Ndim + col];
        } else {
          ((bf16*)Cout)[(size_t)row * Ndim + col] = __float2bfloat16(v);
        }
      }
    }
  }
}

// ---------------- V transpose: [B*N, A] per-head -> vt[bh][64 d][2048 n] ----------------
__global__ __launch_bounds__(256) void vtrans_k(const bf16* __restrict__ vm,
                                                bf16* __restrict__ vt) {
  const int bh = blockIdx.y, b = bh >> 4, h = bh & 15;
  const int n0 = blockIdx.x * 64;
  __shared__ __align__(16) bf16 tile[64 * 72];
  const int tid = threadIdx.x;
#pragma unroll
  for (int i = 0; i < 2; i++) {
    int c = i * 256 + tid;
    int r = c >> 3, cw = c & 7;
    bf16x8 v = *reinterpret_cast<const bf16x8*>(vm + (size_t)(b * Nn + n0 + r) * Aa + h * HDd + cw * 8);
    *reinterpret_cast<bf16x8*>(tile + r * 72 + cw * 8) = v;
  }
  __syncthreads();
#pragma unroll
  for (int i = 0; i < 2; i++) {
    int c = i * 256 + tid;
    int d = c >> 3, ncw = c & 7;
    alignas(16) bf16 tmp[8];
#pragma unroll
    for (int e = 0; e < 8; e++) tmp[e] = tile[(ncw * 8 + e) * 72 + d];
    *reinterpret_cast<bf16x8*>(vt + (size_t)(bh * HDd + d) * Nn + n0 + ncw * 8) =
        *reinterpret_cast<bf16x8*>(tmp);
  }
}

// ---------------- Flash attention, swapped-operand 32x32 MFMA ----------------
// grid = (bh, qblk): all q-blocks of one (b,h) land on one XCD -> K/V L2-hit.
// Softmax fully in-register; P->bf16 via v_cvt_pk_bf16_f32; PV fragment
// exchange via v_permlane32_swap_b32 (T12); defer-max THR=8 (T13).
__global__ __launch_bounds__(256) void attn_k(const bf16* __restrict__ qm,
                                              const bf16* __restrict__ km,
                                              const bf16* __restrict__ vtm,
                                              bf16* __restrict__ om) {
  const int bh = blockIdx.x, b = bh >> 4, h = bh & 15;
  const int tid = threadIdx.x;
  const int wv = tid >> 6, lane = tid & 63;
  const int l31 = lane & 31, hi = lane >> 5, l7 = lane & 7;

  // SMEM elems: K[buf] = +buf*4096, Vt[buf] = +8192+buf*4096 (each 64x64 bf16)
  __shared__ __align__(16) bf16 SMEM[16384];

  const int q0 = blockIdx.y * 128 + wv * 32;

  bf16x8 qf[4];
  const size_t qbase = (size_t)(b * Nn + q0 + l31) * Aa + h * HDd + hi * 8;
#pragma unroll
  for (int dk = 0; dk < 4; dk++)
    qf[dk] = *reinterpret_cast<const bf16x8*>(qm + qbase + dk * 16);

  f32x16 oacc[2];
#pragma unroll
  for (int d = 0; d < 2; d++)
#pragma unroll
    for (int r = 0; r < 16; r++) oacc[d][r] = 0.f;
  float mrun = -__builtin_huge_valf(), lrun = 0.f;

#define STAGE(buf, j0)                                                         \
  {                                                                            \
    _Pragma("unroll")                                                          \
    for (int i = 0; i < 2; i++) {                                              \
      int id = i * 256 + tid;                                                  \
      int row = id >> 3, c = id & 7;                                           \
      int cs = c ^ (row & 7);                                                  \
      GLOAD_LDS16(km + (size_t)(b * Nn + (j0) + row) * Aa + h * HDd + cs * 8,  \
                  SMEM + (buf) * 4096 + (i * 256 + wv * 64) * 8);              \
      GLOAD_LDS16(vtm + (size_t)(bh * 64 + row) * Nn + (j0) + cs * 8,          \
                  SMEM + 8192 + (buf) * 4096 + (i * 256 + wv * 64) * 8);       \
    }                                                                          \
  }

  STAGE(0, 0)
  asm volatile("s_waitcnt vmcnt(0)" ::: "memory");
  __builtin_amdgcn_s_barrier();

  const int NT = Nn / 64;
  for (int jt = 0; jt < NT; jt++) {
    const int cur = jt & 1;
    if (jt + 1 < NT) STAGE(cur ^ 1, (jt + 1) * 64)
    const bf16* KBc = SMEM + cur * 4096;
    const bf16* VBc = SMEM + 8192 + cur * 4096;

    // ---- QK^T (swapped): sacc[t]: S^T rows (keys) t*32.., col q=l31 ----
    f32x16 sacc[2];
#pragma unroll
    for (int t = 0; t < 2; t++)
#pragma unroll
      for (int r = 0; r < 16; r++) sacc[t][r] = 0.f;
#pragma unroll
    for (int t = 0; t < 2; t++) {
#pragma unroll
      for (int dk = 0; dk < 4; dk++) {
        const int row = t * 32 + l31;
        const bf16x8 kf = *reinterpret_cast<const bf16x8*>(
            KBc + row * 64 + (((hi + 2 * dk) ^ l7) * 8));
        sacc[t] = __builtin_amdgcn_mfma_f32_32x32x16_bf16(kf, qf[dk], sacc[t], 0, 0, 0);
      }
    }

    // ---- online softmax, per-lane (one q row, 32 of 64 keys) ----
    float tm = fmaxf(sacc[0][0], sacc[0][1]);
#pragma unroll
    for (int r = 2; r < 16; r++) tm = fmaxf(tm, sacc[0][r]);
#pragma unroll
    for (int r = 0; r < 16; r++) tm = fmaxf(tm, sacc[1][r]);
    tm = fmaxf(tm, __shfl_xor(tm, 32));

    if (!__all(tm <= mrun + 8.f)) {     // defer-max (T13)
      const float nmv = fmaxf(mrun, tm);
      const float corr = exp2f((mrun - nmv) * LOG2E);
      mrun = nmv;
      lrun *= corr;
#pragma unroll
      for (int d = 0; d < 2; d++)
#pragma unroll
        for (int r = 0; r < 16; r++) oacc[d][r] *= corr;
    }
    const float nmL = mrun * LOG2E;
    float ps0 = 0.f, ps1 = 0.f, ps2 = 0.f, ps3 = 0.f;
    uint32_t Wx[2][8];
#pragma unroll
    for (int t = 0; t < 2; t++) {
#pragma unroll
      for (int j = 0; j < 8; j++) {
        const float p0 = exp2f(fmaf(sacc[t][2 * j], LOG2E, -nmL));
        const float p1 = exp2f(fmaf(sacc[t][2 * j + 1], LOG2E, -nmL));
        if (j & 2) { if (j & 1) ps3 += p0 + p1; else ps2 += p0 + p1; }
        else       { if (j & 1) ps1 += p0 + p1; else ps0 += p0 + p1; }
        uint32_t w;
        asm("v_cvt_pk_bf16_f32 %0, %1, %2" : "=v"(w) : "v"(p0), "v"(p1));
        Wx[t][j] = w;
      }
    }
    float ps = (ps0 + ps1) + (ps2 + ps3);
    ps += __shfl_xor(ps, 32);
    lrun += ps;

    // ---- PV (swapped): oacc[dh] += mfma(Vt-frag, P^T-frag) ----
#pragma unroll
    for (int ks = 0; ks < 4; ks++) {
      const int tt = ks >> 1, bse = (ks & 1) * 4;
      uint32_t w0 = Wx[tt][bse + 0], w1 = Wx[tt][bse + 1];
      uint32_t w2 = Wx[tt][bse + 2], w3 = Wx[tt][bse + 3];
      asm("v_permlane32_swap_b32 %0, %1" : "+v"(w0), "+v"(w2));
      asm("v_permlane32_swap_b32 %0, %1" : "+v"(w1), "+v"(w3));
      u32x4v w4;
      w4[0] = w0; w4[1] = w1; w4[2] = w2; w4[3] = w3;
      const bf16x8 pf = __builtin_bit_cast(bf16x8, w4);
#pragma unroll
      for (int dh = 0; dh < 2; dh++) {
        const int row = dh * 32 + l31;
        const bf16x8 vf = *reinterpret_cast<const bf16x8*>(
            VBc + row * 64 + (((hi + 2 * ks) ^ l7) * 8));
        oacc[dh] = __builtin_amdgcn_mfma_f32_32x32x16_bf16(vf, pf, oacc[dh], 0, 0, 0);
      }
    }

    if (jt + 1 < NT) {
      asm volatile("s_waitcnt vmcnt(0)" ::: "memory");
      __builtin_amdgcn_s_barrier();
    }
  }

  // ---- epilogue: O^T regs -> LDS transpose -> coalesced global store ----
  __syncthreads();
  bf16* ob = SMEM + wv * (32 * 72);
  const float inv = 1.f / lrun;
#pragma unroll
  for (int dh = 0; dh < 2; dh++) {
#pragma unroll
    for (int r = 0; r < 16; r++) {
      const int d = (r & 3) + 8 * (r >> 2) + 4 * hi + 32 * dh;
      ob[l31 * 72 + d] = __float2bfloat16(oacc[dh][r] * inv);
    }
  }
  __syncthreads();
  const int qp = lane >> 1, half = lane & 1;
  const size_t orow = (size_t)(b * Nn + q0 + qp) * Aa + h * HDd + half * 32;
#pragma unroll
  for (int e = 0; e < 2; e++) {
    bf16x8 v0 = *reinterpret_cast<const bf16x8*>(ob + qp * 72 + half * 32 + e * 16);
    bf16x8 v1 = *reinterpret_cast<const bf16x8*>(ob + qp * 72 + half * 32 + e * 16 + 8);
    *reinterpret_cast<bf16x8*>(om + orow + e * 16) = v0;
    *reinterpret_cast<bf16x8*>(om + orow + e * 16 + 8) = v1;
  }
}

// ---------------- host launch ----------------
extern "C" void kernel_launch(void* const* d_in, const int* in_sizes, int n_in,
                              void* d_out, int out_size, void* d_ws, size_t ws_size,
                              hipStream_t stream) {
  const float* x    = (const float*)d_in[0];
  const float* wq   = (const float*)d_in[2];
  const float* bq   = (const float*)d_in[3];
  const float* wk   = (const float*)d_in[4];
  const float* bk   = (const float*)d_in[5];
  const float* wv   = (const float*)d_in[6];
  const float* bv   = (const float*)d_in[7];
  const float* wo   = (const float*)d_in[8];
  const float* bo   = (const float*)d_in[9];
  const float* w1   = (const float*)d_in[10];
  const float* b1   = (const float*)d_in[11];
  const float* w2   = (const float*)d_in[12];
  const float* b2   = (const float*)d_in[13];
  const float* ln1g = (const float*)d_in[14];
  const float* ln1b = (const float*)d_in[15];
  const float* ln2g = (const float*)d_in[16];
  const float* ln2b = (const float*)d_in[17];
  float* out = (float*)d_out;

  uint8_t* ws = (uint8_t*)d_ws;
  const size_t MB = (size_t)1 << 20;
  bf16* wq_b = (bf16*)(ws + 0 * MB);
  bf16* wk_b = (bf16*)(ws + 2 * MB);
  bf16* wv_b = (bf16*)(ws + 4 * MB);
  bf16* wo_b = (bf16*)(ws + 6 * MB);
  bf16* w1_b = (bf16*)(ws + 8 * MB);
  bf16* w2_b = (bf16*)(ws + 16 * MB);
  bf16* h_b  = (bf16*)(ws + 24 * MB);  // reused as h2 after attention block
  bf16* q_b  = (bf16*)(ws + 40 * MB);
  bf16* k_b  = (bf16*)(ws + 56 * MB);
  bf16* v_b  = (bf16*)(ws + 72 * MB);
  bf16* vt_b = (bf16*)(ws + 88 * MB);
  bf16* o_b  = (bf16*)(ws + 104 * MB);
  float* x2  = (float*)(ws + 120 * MB);
  bf16* mid  = (bf16*)(ws + 40 * MB);  // overlaps q/k/v/vt (dead by then)

  const float SCALE = 0.03125f;  // 1024^-0.5

  cvt_k<<<1024, 256, 0, stream>>>(wq, wq_b, 262144);
  cvt_k<<<1024, 256, 0, stream>>>(wk, wk_b, 262144);
  cvt_k<<<1024, 256, 0, stream>>>(wv, wv_b, 262144);
  cvt_k<<<1024, 256, 0, stream>>>(wo, wo_b, 262144);
  cvt_k<<<4096, 256, 0, stream>>>(w1, w1_b, 1048576);
  cvt_k<<<4096, 256, 0, stream>>>(w2, w2_b, 1048576);

  ln_k<<<Mm, 256, 0, stream>>>(x, ln1g, ln1b, h_b);

  dim3 gP(Aa / 128, Mm / 128);  // (8, 64)
  gemm_bt<0><<<gP, 256, 0, stream>>>(h_b, wq_b, bq, nullptr, q_b, Aa, Dd, SCALE);
  gemm_bt<0><<<gP, 256, 0, stream>>>(h_b, wk_b, bk, nullptr, k_b, Aa, Dd, 1.f);
  gemm_bt<0><<<gP, 256, 0, stream>>>(h_b, wv_b, bv, nullptr, v_b, Aa, Dd, 1.f);

  vtrans_k<<<dim3(Nn / 64, Bb * Hh), 256, 0, stream>>>(v_b, vt_b);
  attn_k<<<dim3(Bb * Hh, Nn / 128), 256, 0, stream>>>(q_b, k_b, vt_b, o_b);

  gemm_bt<1><<<gP, 256, 0, stream>>>(o_b, wo_b, bo, x, x2, Dd, Aa, 1.f);

  ln_k<<<Mm, 256, 0, stream>>>(x2, ln2g, ln2b, h_b);

  dim3 gF(DFF / 128, Mm / 128);  // (32, 64)
  gemm_bt<2><<<gF, 256, 0, stream>>>(h_b, w1_b, b1, nullptr, mid, DFF, Dd, 1.f);
  gemm_bt<1><<<gP, 256, 0, stream>>>(mid, w2_b, b2, x2, out, Dd, DFF, 1.f);
}

// Round 6
// 580.610 us; speedup vs baseline: 1.3688x; 1.1354x over previous
//
#include <hip/hip_runtime.h>
#include <hip/hip_bf16.h>
#include <stdint.h>

#define Bb 4
#define Nn 2048
#define Dd 1024
#define Hh 16
#define DFF 4096
#define Mm (Bb*Nn)
#define QKVLD 3072

typedef __bf16 bf16x8 __attribute__((ext_vector_type(8)));
typedef float f32x4 __attribute__((ext_vector_type(4)));
typedef float f32x16 __attribute__((ext_vector_type(16)));
typedef uint32_t u32x4v __attribute__((ext_vector_type(4)));
typedef unsigned short ushort_t;
using bf16 = __hip_bfloat16;

#define LOG2E 1.44269504088896340736f

__device__ inline ushort_t f2bfu(float f) {
  uint32_t u = __builtin_bit_cast(uint32_t, f);
  uint32_t r = u + 0x7fffu + ((u >> 16) & 1u);
  return (ushort_t)(r >> 16);
}

#define GLOAD_LDS16(gsrc, ldst)                                                \
  __builtin_amdgcn_global_load_lds(                                            \
      (const __attribute__((address_space(1))) void*)(gsrc),                   \
      (__attribute__((address_space(3))) void*)(ldst), 16, 0, 0)

// ---------------- f32 -> bf16 convert (optional scale) ----------------
__global__ __launch_bounds__(256) void cvt_k(const float* __restrict__ in,
                                             bf16* __restrict__ out, int n4,
                                             float s) {
  int i = blockIdx.x * 256 + threadIdx.x;
  if (i >= n4) return;
  float4 v = reinterpret_cast<const float4*>(in)[i];
  ushort4 o;
  o.x = f2bfu(v.x * s); o.y = f2bfu(v.y * s);
  o.z = f2bfu(v.z * s); o.w = f2bfu(v.w * s);
  reinterpret_cast<ushort4*>(out)[i] = o;
}

// ---------------- concat qkv bias (scale on q part) ----------------
__global__ __launch_bounds__(256) void bcat_k(const float* __restrict__ bq,
                                              const float* __restrict__ bk,
                                              const float* __restrict__ bv,
                                              float* __restrict__ o) {
  int i = blockIdx.x * 256 + threadIdx.x;
  float v = i < 1024 ? bq[i] * 0.03125f : (i < 2048 ? bk[i - 1024] : bv[i - 2048]);
  o[i] = v;
}

// ---------------- LayerNorm (per row of 1024), f32 in -> bf16 out ----------------
__global__ __launch_bounds__(256) void ln_k(const float* __restrict__ x,
                                            const float* __restrict__ g,
                                            const float* __restrict__ b,
                                            bf16* __restrict__ out) {
  const int row = blockIdx.x;
  const int t = threadIdx.x;
  const float4 v = reinterpret_cast<const float4*>(x + (size_t)row * Dd)[t];
  float s = v.x + v.y + v.z + v.w;
  float sq = v.x * v.x + v.y * v.y + v.z * v.z + v.w * v.w;
#pragma unroll
  for (int m = 1; m < 64; m <<= 1) {
    s += __shfl_xor(s, m);
    sq += __shfl_xor(sq, m);
  }
  __shared__ float red[8];
  if ((t & 63) == 0) { red[t >> 6] = s; red[4 + (t >> 6)] = sq; }
  __syncthreads();
  s = red[0] + red[1] + red[2] + red[3];
  sq = red[4] + red[5] + red[6] + red[7];
  const float mean = s * (1.f / Dd);
  const float rstd = rsqrtf(sq * (1.f / Dd) - mean * mean + 1e-5f);
  const float4 gg = reinterpret_cast<const float4*>(g)[t];
  const float4 bb = reinterpret_cast<const float4*>(b)[t];
  ushort4 o;
  o.x = f2bfu((v.x - mean) * rstd * gg.x + bb.x);
  o.y = f2bfu((v.y - mean) * rstd * gg.y + bb.y);
  o.z = f2bfu((v.z - mean) * rstd * gg.z + bb.z);
  o.w = f2bfu((v.w - mean) * rstd * gg.w + bb.w);
  reinterpret_cast<ushort4*>(out + (size_t)row * Dd)[t] = o;
}

// =======================================================================
// 2-phase double-buffered GEMM (T3-minimum recipe, same sync structure as
// the proven attn_k loop): STAGE(next) -> compute(cur) -> vmcnt(0) -> bar.
// 128x128 tile, BK=64, 4 waves (2x2). LDS rows = 128 B (one matrix row);
// 16B slot s of row r holds col-chunk s^(r&7)  [R4-verified swizzle, rule
// #21: inverse-permuted global source, linear gload_lds dest].
// EPI 0: +bias -> bf16; 1: +bias+resid -> f32; 2: relu(+bias) -> bf16
// =======================================================================
template <int EPI>
__global__ __launch_bounds__(256) void gemm_bt(const bf16* __restrict__ Amat,
                                               const bf16* __restrict__ Wmat,
                                               const float* __restrict__ bias,
                                               const float* __restrict__ resid,
                                               void* __restrict__ Cout,
                                               int Ndim, int Kdim) {
  __shared__ __align__(16) bf16 As[2][128 * 64];
  __shared__ __align__(16) bf16 Bs[2][128 * 64];
  const int tid = threadIdx.x;
  const int wave = tid >> 6, lane = tid & 63;
  const int g16 = lane >> 4, l15 = lane & 15;
  const int wm = wave >> 1, wn = wave & 1;
  const int tmb = blockIdx.y * 128, tnb = blockIdx.x * 128;

  const f32x4 zero = {0.f, 0.f, 0.f, 0.f};
  f32x4 acc[4][4];
#pragma unroll
  for (int f = 0; f < 4; f++)
#pragma unroll
    for (int g = 0; g < 4; g++) acc[f][g] = zero;

  // 4 chunks/thread/matrix: chunk id -> row id>>3, source col-chunk
  // (id&7)^(row&7), linear LDS dst (wave-uniform base + lane*16)
#define STG(buf, k0)                                                           \
  {                                                                            \
    _Pragma("unroll")                                                          \
    for (int i = 0; i < 4; i++) {                                              \
      int id = i * 256 + tid;                                                  \
      int row = id >> 3;                                                       \
      int cs = (id & 7) ^ (row & 7);                                           \
      GLOAD_LDS16(Amat + (size_t)(tmb + row) * Kdim + (k0) + cs * 8,           \
                  As[buf] + (i * 256 + wave * 64) * 8);                        \
      GLOAD_LDS16(Wmat + (size_t)(tnb + row) * Kdim + (k0) + cs * 8,           \
                  Bs[buf] + (i * 256 + wave * 64) * 8);                        \
    }                                                                          \
  }

  STG(0, 0)
  asm volatile("s_waitcnt vmcnt(0)" ::: "memory");
  __builtin_amdgcn_s_barrier();

  const int NT = Kdim >> 6;
  for (int kt = 0; kt < NT; kt++) {
    const int cur = kt & 1;
    if (kt + 1 < NT) STG(cur ^ 1, (kt + 1) * 64)

#pragma unroll
    for (int ks = 0; ks < 2; ks++) {
      bf16x8 af[4], bfr[4];
#pragma unroll
      for (int f = 0; f < 4; f++) {
        const int rA = wm * 64 + f * 16 + l15;
        const int rB = wn * 64 + f * 16 + l15;
        const int sl = ((ks * 4 + g16) ^ (l15 & 7)) * 8;
        af[f] = *reinterpret_cast<const bf16x8*>(As[cur] + rA * 64 + sl);
        bfr[f] = *reinterpret_cast<const bf16x8*>(Bs[cur] + rB * 64 + sl);
      }
#pragma unroll
      for (int f = 0; f < 4; f++)
#pragma unroll
        for (int g = 0; g < 4; g++)
          acc[f][g] = __builtin_amdgcn_mfma_f32_16x16x32_bf16(af[f], bfr[g],
                                                              acc[f][g], 0, 0, 0);
    }

    asm volatile("s_waitcnt vmcnt(0)" ::: "memory");
    __builtin_amdgcn_s_barrier();
  }
#undef STG

#pragma unroll
  for (int f = 0; f < 4; f++) {
#pragma unroll
    for (int g = 0; g < 4; g++) {
      const int col = tnb + wn * 64 + g * 16 + l15;
      const float bi = bias[col];
#pragma unroll
      for (int r = 0; r < 4; r++) {
        const int row = tmb + wm * 64 + f * 16 + g16 * 4 + r;
        float v = acc[f][g][r] + bi;
        if constexpr (EPI == 2) v = fmaxf(v, 0.f);
        if constexpr (EPI == 1) {
          ((float*)Cout)[(size_t)row * Ndim + col] =
              v + resid[(size_t)row * Ndim + col];
        } else {
          ((bf16*)Cout)[(size_t)row * Ndim + col] = __float2bfloat16(v);
        }
      }
    }
  }
}

// ---------------- V transpose: qkv V-section -> vt[bh][64 d][2048 n] ----------------
__global__ __launch_bounds__(256) void vtrans_k(const bf16* __restrict__ vm,
                                                bf16* __restrict__ vt) {
  const int bh = blockIdx.y, b = bh >> 4, h = bh & 15;
  const int n0 = blockIdx.x * 64;
  __shared__ __align__(16) bf16 tile[64 * 72];
  const int tid = threadIdx.x;
#pragma unroll
  for (int i = 0; i < 2; i++) {
    int c = i * 256 + tid;
    int r = c >> 3, cw = c & 7;
    bf16x8 v = *reinterpret_cast<const bf16x8*>(
        vm + (size_t)(b * Nn + n0 + r) * QKVLD + h * 64 + cw * 8);
    *reinterpret_cast<bf16x8*>(tile + r * 72 + cw * 8) = v;
  }
  __syncthreads();
#pragma unroll
  for (int i = 0; i < 2; i++) {
    int c = i * 256 + tid;
    int d = c >> 3, ncw = c & 7;
    alignas(16) bf16 tmp[8];
#pragma unroll
    for (int e = 0; e < 8; e++) tmp[e] = tile[(ncw * 8 + e) * 72 + d];
    *reinterpret_cast<bf16x8*>(vt + (size_t)(bh * 64 + d) * Nn + n0 + ncw * 8) =
        *reinterpret_cast<bf16x8*>(tmp);
  }
}

// ---------------- Flash attention (swapped 32x32 MFMA, in-reg softmax) ----------------
__global__ __launch_bounds__(256) void attn_k(const bf16* __restrict__ qm,
                                              const bf16* __restrict__ km,
                                              const bf16* __restrict__ vtm,
                                              bf16* __restrict__ om) {
  const int bh = blockIdx.x, b = bh >> 4, h = bh & 15;
  const int tid = threadIdx.x;
  const int wv = tid >> 6, lane = tid & 63;
  const int l31 = lane & 31, hi = lane >> 5, l7 = lane & 7;

  __shared__ __align__(16) bf16 SMEM[16384];

  const int q0 = blockIdx.y * 128 + wv * 32;

  bf16x8 qf[4];
  const size_t qbase = (size_t)(b * Nn + q0 + l31) * QKVLD + h * 64 + hi * 8;
#pragma unroll
  for (int dk = 0; dk < 4; dk++)
    qf[dk] = *reinterpret_cast<const bf16x8*>(qm + qbase + dk * 16);

  f32x16 oacc[2];
#pragma unroll
  for (int d = 0; d < 2; d++)
#pragma unroll
    for (int r = 0; r < 16; r++) oacc[d][r] = 0.f;
  float mrun = -__builtin_huge_valf(), lrun = 0.f;

#define STAGE(buf, j0)                                                         \
  {                                                                            \
    _Pragma("unroll")                                                          \
    for (int i = 0; i < 2; i++) {                                              \
      int id = i * 256 + tid;                                                  \
      int row = id >> 3, c = id & 7;                                           \
      int cs = c ^ (row & 7);                                                  \
      GLOAD_LDS16(km + (size_t)(b * Nn + (j0) + row) * QKVLD + h * 64 + cs * 8,\
                  SMEM + (buf) * 4096 + (i * 256 + wv * 64) * 8);              \
      GLOAD_LDS16(vtm + (size_t)(bh * 64 + row) * Nn + (j0) + cs * 8,          \
                  SMEM + 8192 + (buf) * 4096 + (i * 256 + wv * 64) * 8);       \
    }                                                                          \
  }

  STAGE(0, 0)
  asm volatile("s_waitcnt vmcnt(0)" ::: "memory");
  __builtin_amdgcn_s_barrier();

  const int NT = Nn / 64;
  for (int jt = 0; jt < NT; jt++) {
    const int cur = jt & 1;
    if (jt + 1 < NT) STAGE(cur ^ 1, (jt + 1) * 64)
    const bf16* KBc = SMEM + cur * 4096;
    const bf16* VBc = SMEM + 8192 + cur * 4096;

    f32x16 sacc[2];
#pragma unroll
    for (int t = 0; t < 2; t++)
#pragma unroll
      for (int r = 0; r < 16; r++) sacc[t][r] = 0.f;
#pragma unroll
    for (int t = 0; t < 2; t++) {
#pragma unroll
      for (int dk = 0; dk < 4; dk++) {
        const int row = t * 32 + l31;
        const bf16x8 kf = *reinterpret_cast<const bf16x8*>(
            KBc + row * 64 + (((hi + 2 * dk) ^ l7) * 8));
        sacc[t] = __builtin_amdgcn_mfma_f32_32x32x16_bf16(kf, qf[dk], sacc[t], 0, 0, 0);
      }
    }

    float tm = fmaxf(sacc[0][0], sacc[0][1]);
#pragma unroll
    for (int r = 2; r < 16; r++) tm = fmaxf(tm, sacc[0][r]);
#pragma unroll
    for (int r = 0; r < 16; r++) tm = fmaxf(tm, sacc[1][r]);
    tm = fmaxf(tm, __shfl_xor(tm, 32));

    if (!__all(tm <= mrun + 8.f)) {
      const float nmv = fmaxf(mrun, tm);
      const float corr = exp2f((mrun - nmv) * LOG2E);
      mrun = nmv;
      lrun *= corr;
#pragma unroll
      for (int d = 0; d < 2; d++)
#pragma unroll
        for (int r = 0; r < 16; r++) oacc[d][r] *= corr;
    }
    const float nmL = mrun * LOG2E;
    float ps0 = 0.f, ps1 = 0.f, ps2 = 0.f, ps3 = 0.f;
    uint32_t Wx[2][8];
#pragma unroll
    for (int t = 0; t < 2; t++) {
#pragma unroll
      for (int j = 0; j < 8; j++) {
        const float p0 = exp2f(fmaf(sacc[t][2 * j], LOG2E, -nmL));
        const float p1 = exp2f(fmaf(sacc[t][2 * j + 1], LOG2E, -nmL));
        if (j & 2) { if (j & 1) ps3 += p0 + p1; else ps2 += p0 + p1; }
        else       { if (j & 1) ps1 += p0 + p1; else ps0 += p0 + p1; }
        uint32_t w;
        asm("v_cvt_pk_bf16_f32 %0, %1, %2" : "=v"(w) : "v"(p0), "v"(p1));
        Wx[t][j] = w;
      }
    }
    float ps = (ps0 + ps1) + (ps2 + ps3);
    ps += __shfl_xor(ps, 32);
    lrun += ps;

#pragma unroll
    for (int ks = 0; ks < 4; ks++) {
      const int tt = ks >> 1, bse = (ks & 1) * 4;
      uint32_t w0 = Wx[tt][bse + 0], w1 = Wx[tt][bse + 1];
      uint32_t w2 = Wx[tt][bse + 2], w3 = Wx[tt][bse + 3];
      asm("v_permlane32_swap_b32 %0, %1" : "+v"(w0), "+v"(w2));
      asm("v_permlane32_swap_b32 %0, %1" : "+v"(w1), "+v"(w3));
      u32x4v w4;
      w4[0] = w0; w4[1] = w1; w4[2] = w2; w4[3] = w3;
      const bf16x8 pf = __builtin_bit_cast(bf16x8, w4);
#pragma unroll
      for (int dh = 0; dh < 2; dh++) {
        const int row = dh * 32 + l31;
        const bf16x8 vf = *reinterpret_cast<const bf16x8*>(
            VBc + row * 64 + (((hi + 2 * ks) ^ l7) * 8));
        oacc[dh] = __builtin_amdgcn_mfma_f32_32x32x16_bf16(vf, pf, oacc[dh], 0, 0, 0);
      }
    }

    if (jt + 1 < NT) {
      asm volatile("s_waitcnt vmcnt(0)" ::: "memory");
      __builtin_amdgcn_s_barrier();
    }
  }

  __syncthreads();
  bf16* ob = SMEM + wv * (32 * 72);
  const float inv = 1.f / lrun;
#pragma unroll
  for (int dh = 0; dh < 2; dh++) {
#pragma unroll
    for (int r = 0; r < 16; r++) {
      const int d = (r & 3) + 8 * (r >> 2) + 4 * hi + 32 * dh;
      ob[l31 * 72 + d] = __float2bfloat16(oacc[dh][r] * inv);
    }
  }
  __syncthreads();
  const int qp = lane >> 1, half = lane & 1;
  const size_t orow = (size_t)(b * Nn + q0 + qp) * 1024 + h * 64 + half * 32;
#pragma unroll
  for (int e = 0; e < 2; e++) {
    bf16x8 v0 = *reinterpret_cast<const bf16x8*>(ob + qp * 72 + half * 32 + e * 16);
    bf16x8 v1 = *reinterpret_cast<const bf16x8*>(ob + qp * 72 + half * 32 + e * 16 + 8);
    *reinterpret_cast<bf16x8*>(om + orow + e * 16) = v0;
    *reinterpret_cast<bf16x8*>(om + orow + e * 16 + 8) = v1;
  }
}

// ---------------- host launch ----------------
extern "C" void kernel_launch(void* const* d_in, const int* in_sizes, int n_in,
                              void* d_out, int out_size, void* d_ws, size_t ws_size,
                              hipStream_t stream) {
  const float* x    = (const float*)d_in[0];
  const float* wq   = (const float*)d_in[2];
  const float* bq   = (const float*)d_in[3];
  const float* wk   = (const float*)d_in[4];
  const float* bk   = (const float*)d_in[5];
  const float* wv   = (const float*)d_in[6];
  const float* bv   = (const float*)d_in[7];
  const float* wo   = (const float*)d_in[8];
  const float* bo   = (const float*)d_in[9];
  const float* w1   = (const float*)d_in[10];
  const float* b1   = (const float*)d_in[11];
  const float* w2   = (const float*)d_in[12];
  const float* b2   = (const float*)d_in[13];
  const float* ln1g = (const float*)d_in[14];
  const float* ln1b = (const float*)d_in[15];
  const float* ln2g = (const float*)d_in[16];
  const float* ln2b = (const float*)d_in[17];
  float* out = (float*)d_out;

  uint8_t* ws = (uint8_t*)d_ws;
  const size_t MB = (size_t)1 << 20;
  bf16* wqkv_b = (bf16*)(ws + 0 * MB);    // 6 MB  [3072][1024]
  bf16* wo_b   = (bf16*)(ws + 6 * MB);    // 2 MB
  bf16* w1_b   = (bf16*)(ws + 8 * MB);    // 8 MB
  bf16* w2_b   = (bf16*)(ws + 16 * MB);   // 8 MB
  bf16* h_b    = (bf16*)(ws + 24 * MB);   // 16 MB (LN1 out, reused for LN2 out)
  bf16* qkv_b  = (bf16*)(ws + 40 * MB);   // 48 MB [8192][3072]
  bf16* vt_b   = (bf16*)(ws + 88 * MB);   // 16 MB
  bf16* o_b    = (bf16*)(ws + 104 * MB);  // 16 MB (attn out)
  float* x2    = (float*)(ws + 120 * MB); // 32 MB
  bf16* mid    = (bf16*)(ws + 40 * MB);   // 64 MB, overlaps qkv+vt (dead by MLP1)
  float* bqkv  = (float*)(ws + 104 * MB); // 12 KB, dead before attn writes o_b

  cvt_k<<<1024, 256, 0, stream>>>(wq, wqkv_b,            262144, 0.03125f);
  cvt_k<<<1024, 256, 0, stream>>>(wk, wqkv_b + 1048576,  262144, 1.f);
  cvt_k<<<1024, 256, 0, stream>>>(wv, wqkv_b + 2097152,  262144, 1.f);
  cvt_k<<<1024, 256, 0, stream>>>(wo, wo_b, 262144, 1.f);
  cvt_k<<<4096, 256, 0, stream>>>(w1, w1_b, 1048576, 1.f);
  cvt_k<<<4096, 256, 0, stream>>>(w2, w2_b, 1048576, 1.f);
  bcat_k<<<12, 256, 0, stream>>>(bq, bk, bv, bqkv);

  ln_k<<<Mm, 256, 0, stream>>>(x, ln1g, ln1b, h_b);

  // fused QKV GEMM: [8192,1024] x [3072,1024]^T -> [8192,3072] bf16
  gemm_bt<0><<<dim3(QKVLD / 128, Mm / 128), 256, 0, stream>>>(
      h_b, wqkv_b, bqkv, nullptr, qkv_b, QKVLD, Dd);

  vtrans_k<<<dim3(Nn / 64, Bb * Hh), 256, 0, stream>>>(qkv_b + 2048, vt_b);
  attn_k<<<dim3(Bb * Hh, Nn / 128), 256, 0, stream>>>(qkv_b, qkv_b + 1024, vt_b, o_b);

  // O-projection + residual -> f32 x2
  gemm_bt<1><<<dim3(Dd / 128, Mm / 128), 256, 0, stream>>>(
      o_b, wo_b, bo, x, x2, Dd, Dd);

  ln_k<<<Mm, 256, 0, stream>>>(x2, ln2g, ln2b, h_b);

  // MLP1: relu -> bf16 mid
  gemm_bt<2><<<dim3(DFF / 128, Mm / 128), 256, 0, stream>>>(
      h_b, w1_b, b1, nullptr, mid, DFF, Dd);
  // MLP2: + resid -> f32 out
  gemm_bt<1><<<dim3(Dd / 128, Mm / 128), 256, 0, stream>>>(
      mid, w2_b, b2, x2, out, Dd, DFF);
}